// Round 6
// baseline (208.751 us; speedup 1.0000x reference)
//
#include <hip/hip_runtime.h>

typedef __attribute__((ext_vector_type(8))) short bf16x8;
typedef __attribute__((ext_vector_type(4))) float f32x4;

#define LDK 40   // padded A-tile LDS row stride in shorts (80 B)

__device__ __forceinline__ float bf2f(unsigned short u) {
    union { unsigned int i; float f; } v; v.i = ((unsigned int)u) << 16; return v.f;
}
__device__ __forceinline__ unsigned short f2bf(float f) {
    union { float f; unsigned int i; } v; v.f = f;
    unsigned int x = v.i;
    return (unsigned short)((x + 0x7FFFu + ((x >> 16) & 1u)) >> 16);  // RNE
}
__device__ __forceinline__ void gload16(const void* g, void* l) {
    __builtin_amdgcn_global_load_lds(
        (const __attribute__((address_space(1))) unsigned int*)g,
        (__attribute__((address_space(3))) unsigned int*)l, 16, 0, 0);
}

// ---------------------------------------------------------------------------
// Bt[n][k] = bf16(B[k][n]);  B = proj_w [K=1024][N=256]
// ---------------------------------------------------------------------------
__global__ __launch_bounds__(256) void transpose_b_kernel(
    const float* __restrict__ B, unsigned short* __restrict__ Bt, int K, int N)
{
    __shared__ float tile[32][33];
    int kb = blockIdx.x % (K / 32);
    int nb = blockIdx.x / (K / 32);
    int k0 = kb * 32, n0 = nb * 32;
    int tx = threadIdx.x & 31, ty = threadIdx.x >> 5;
    #pragma unroll
    for (int i = 0; i < 4; ++i)
        tile[ty + 8 * i][tx] = B[(size_t)(k0 + ty + 8 * i) * N + n0 + tx];
    __syncthreads();
    #pragma unroll
    for (int i = 0; i < 4; ++i)
        Bt[(size_t)(n0 + ty + 8 * i) * K + k0 + tx] = f2bf(tile[tx][ty + 8 * i]);
}

// ---------------------------------------------------------------------------
// enc_bf = bf16(A @ B + bias); logit[row] += sum_c (A@B+bias)[row,c]*attn_w[c]
// 64x32 tile (MxN), BK=32, 4 waves (each 16 rows x 32 cols = 2 MFMA frags).
// Grid = (M/64)*(N/32) = 2048 blocks -> 8 blocks/CU x 4 waves = 32 waves/CU
// (100% occupancy, __launch_bounds__(256,8)). Simple 1-barrier dbuf loop.
// ---------------------------------------------------------------------------
__global__ __launch_bounds__(256, 8) void gemm_mfma_kernel(
    const float* __restrict__ A, const unsigned short* __restrict__ Bt,
    const float* __restrict__ bias, const float* __restrict__ attn_w,
    unsigned short* __restrict__ C, float* __restrict__ logit,
    int M, int N, int K)
{
    __shared__ __attribute__((aligned(16))) unsigned short AsA[2][64 * LDK];
    __shared__ __attribute__((aligned(16))) unsigned short AsB[2][32 * 32];

    const int tid = threadIdx.x;
    const int bid = blockIdx.x;
    // XCD-chunked swizzle (grid 2048 = 8*256, bijective): XCD x gets 32
    // consecutive 64-row A panels x all 8 bn -> A panel L2-reused 8x.
    const int xcd = bid & 7;
    const int j   = bid >> 3;              // 0..255
    const int bn  = (j & 7) * 32;
    const int bm  = (xcd * 32 + (j >> 3)) * 64;

    const int lane = tid & 63;
    const int wave = tid >> 6;             // 0..3
    const int c15  = lane & 15;
    const int g4   = lane >> 4;
    const int kg8  = g4 * 8;
    const int slB  = (g4 ^ ((c15 >> 1) & 3)) * 8;   // swizzled B read slot

    // A staging: thread covers 8 contiguous k of one row (2 float4 loads)
    const int arow = tid >> 2;             // 0..63
    const int akq  = (tid & 3) * 8;        // 0,8,16,24
    const float* Aptr = A + (size_t)(bm + arow) * K + akq;

    // B staging via global_load_lds (threads 0..127, waves 0-1):
    // LDS dest linear: base + lane*16B; source slot swizzled for bank spread
    const int brow  = (tid & 127) >> 2;    // 0..31
    const int bslot = (tid & 3) ^ ((tid >> 3) & 3);
    const unsigned short* Bptr = Bt + (size_t)(bn + brow) * K + bslot * 8;

    f32x4 acc[2];
    acc[0] = (f32x4){0.f, 0.f, 0.f, 0.f};
    acc[1] = (f32x4){0.f, 0.f, 0.f, 0.f};

    const int nk = K / 32;                 // 32

    // ---- prologue: stage tile 0 into buf 0 ----
    if (tid < 128) gload16(Bptr, &AsB[0][(tid >> 6) * 512]);
    {
        float4 a0 = *(const float4*)(Aptr);
        float4 a1 = *(const float4*)(Aptr + 4);
        unsigned short tmp[8];
        const float* af = (const float*)&a0;
        #pragma unroll
        for (int i = 0; i < 4; ++i) tmp[i] = f2bf(af[i]);
        af = (const float*)&a1;
        #pragma unroll
        for (int i = 0; i < 4; ++i) tmp[4 + i] = f2bf(af[i]);
        *(bf16x8*)&AsA[0][arow * LDK + akq] = *(bf16x8*)&tmp[0];
    }
    __syncthreads();

    // ---- main loop: 1 barrier/iter ----
    for (int t = 0; t < nk; ++t) {
        const int s = t & 1;
        float4 a0n, a1n;
        const bool more = (t + 1 < nk);
        if (more) {
            if (tid < 128) gload16(Bptr + (t + 1) * 32, &AsB[1 - s][(tid >> 6) * 512]);
            a0n = *(const float4*)(Aptr + (t + 1) * 32);
            a1n = *(const float4*)(Aptr + (t + 1) * 32 + 4);
        }
        bf16x8 af  = *(bf16x8*)&AsA[s][(wave * 16 + c15) * LDK + kg8];
        bf16x8 bf0 = *(bf16x8*)&AsB[s][c15 * 32 + slB];
        bf16x8 bf1 = *(bf16x8*)&AsB[s][(16 + c15) * 32 + slB];
        acc[0] = __builtin_amdgcn_mfma_f32_16x16x32_bf16(af, bf0, acc[0], 0, 0, 0);
        acc[1] = __builtin_amdgcn_mfma_f32_16x16x32_bf16(af, bf1, acc[1], 0, 0, 0);
        if (more) {
            unsigned short tmp[8];
            const float* afp = (const float*)&a0n;
            #pragma unroll
            for (int i = 0; i < 4; ++i) tmp[i] = f2bf(afp[i]);
            afp = (const float*)&a1n;
            #pragma unroll
            for (int i = 0; i < 4; ++i) tmp[4 + i] = f2bf(afp[i]);
            *(bf16x8*)&AsA[1 - s][arow * LDK + akq] = *(bf16x8*)&tmp[0];
        }
        __syncthreads();
    }

    // ---- epilogue: C store + fused logit partials ----
    const int col0 = bn + c15;
    const int row0 = bm + wave * 16 + g4 * 4;
    float wsum[4] = {};
    #pragma unroll
    for (int n = 0; n < 2; ++n) {
        float bv  = bias[col0 + n * 16];
        float awv = attn_w[col0 + n * 16];
        #pragma unroll
        for (int i = 0; i < 4; ++i) {
            float cf = acc[n][i] + bv;
            C[(size_t)(row0 + i) * N + col0 + n * 16] = f2bf(cf);
            wsum[i] += cf * awv;
        }
    }
    #pragma unroll
    for (int i = 0; i < 4; ++i) {
        float v = wsum[i];
        v += __shfl_xor(v, 1, 64);
        v += __shfl_xor(v, 2, 64);
        v += __shfl_xor(v, 4, 64);
        v += __shfl_xor(v, 8, 64);
        if (c15 == 0) atomicAdd(&logit[row0 + i], v);
    }
}

// ---------------------------------------------------------------------------
// Query locality sort: counting sort by key = qb*32 + (s>>6)  (256 buckets)
// ---------------------------------------------------------------------------
__global__ __launch_bounds__(256) void hist_kernel(
    const int* __restrict__ s1, const int* __restrict__ s2,
    const int* __restrict__ qb, int* __restrict__ cnt, int Q)
{
    int j = blockIdx.x * 256 + threadIdx.x;
    if (j >= 2 * Q) return;
    int qi = (j < Q) ? j : j - Q;
    int s  = (j < Q) ? s1[qi] : s2[qi];
    atomicAdd(&cnt[qb[qi] * 32 + (s >> 6)], 1);
}

__global__ __launch_bounds__(256) void scan_kernel(
    const int* __restrict__ cnt, int* __restrict__ off)
{
    __shared__ int tmp[256];
    int tid = threadIdx.x;
    int v = cnt[tid];
    tmp[tid] = v;
    __syncthreads();
    #pragma unroll
    for (int d = 1; d < 256; d <<= 1) {
        int x = (tid >= d) ? tmp[tid - d] : 0;
        __syncthreads();
        tmp[tid] += x;
        __syncthreads();
    }
    off[tid] = tmp[tid] - v;   // exclusive
}

__global__ __launch_bounds__(256) void scatter_kernel(
    const int* __restrict__ s1, const int* __restrict__ s2,
    const int* __restrict__ qb, int* __restrict__ off,
    int* __restrict__ perm, int Q)
{
    int j = blockIdx.x * 256 + threadIdx.x;
    if (j >= 2 * Q) return;
    int qi = (j < Q) ? j : j - Q;
    int s  = (j < Q) ? s1[qi] : s2[qi];
    int pos = atomicAdd(&off[qb[qi] * 32 + (s >> 6)], 1);
    perm[pos] = j;
}

// ---------------------------------------------------------------------------
// Span attention: ONE WAVE per (sorted) query; 16-deep hoisted clamped loads.
// Sorted order puts waves touching the same enc region together -> L2 hits.
// ---------------------------------------------------------------------------
__global__ __launch_bounds__(256) void span_kernel(
    const unsigned short* __restrict__ enc, const float* __restrict__ logit,
    const int* __restrict__ s1, const int* __restrict__ e1,
    const int* __restrict__ s2, const int* __restrict__ e2,
    const int* __restrict__ qb, const int* __restrict__ perm,
    float* __restrict__ out, int Q, int seq, int pd)
{
    int lane = threadIdx.x & 63;
    int gid = blockIdx.x * 4 + (threadIdx.x >> 6);
    int q = perm[gid];
    int r  = (q >= Q) ? 1 : 0;
    int qi = q - r * Q;
    int s = r ? s2[qi] : s1[qi];
    int e = r ? e2[qi] : e1[qi];
    int b = qb[qi];
    int len = e - s + 1;                     // 1..32

    const float* lp = logit + (size_t)b * seq + s;
    float lg = (lane < len) ? lp[lane] : -3.4e38f;
    float m = lg;
    #pragma unroll
    for (int off = 32; off; off >>= 1) m = fmaxf(m, __shfl_xor(m, off, 64));
    float p = (lane < len) ? __expf(lg - m) : 0.0f;
    float sum = p;
    #pragma unroll
    for (int off = 32; off; off >>= 1) sum += __shfl_xor(sum, off, 64);
    float inv = 1.0f / sum;

    const unsigned short* ep = enc + ((size_t)b * seq + s) * pd + lane * 4;
    float ax = 0.f, ay = 0.f, az = 0.f, aw = 0.f;

    for (int t0 = 0; t0 < len; t0 += 16) {       // at most 2 chunks
        ushort4 ev[16];
        #pragma unroll
        for (int u = 0; u < 16; ++u) {
            int tc = t0 + u;
            tc = (tc < len) ? tc : (len - 1);    // clamp: avoid NaN from overread
            ev[u] = *(const ushort4*)(ep + (size_t)tc * pd);
        }
        #pragma unroll
        for (int u = 0; u < 16; ++u) {
            float wt = __shfl(p, t0 + u, 64);    // p==0 beyond len
            ax += wt * bf2f(ev[u].x);
            ay += wt * bf2f(ev[u].y);
            az += wt * bf2f(ev[u].z);
            aw += wt * bf2f(ev[u].w);
        }
    }
    float4 res = {ax * inv, ay * inv, az * inv, aw * inv};
    *((float4*)(out + (size_t)q * pd) + lane) = res;
}

// ---------------------------------------------------------------------------
extern "C" void kernel_launch(void* const* d_in, const int* in_sizes, int n_in,
                              void* d_out, int out_size, void* d_ws, size_t ws_size,
                              hipStream_t stream) {
    const float* enc_in = (const float*)d_in[1];
    const int*   s1     = (const int*)d_in[2];
    const int*   e1     = (const int*)d_in[3];
    const int*   qb     = (const int*)d_in[4];
    const int*   s2     = (const int*)d_in[5];
    const int*   e2     = (const int*)d_in[6];
    const float* proj_w = (const float*)d_in[7];
    const float* proj_b = (const float*)d_in[8];
    const float* attn_w = (const float*)d_in[9];
    float* out = (float*)d_out;

    const int Q   = in_sizes[2];            // 8192
    const int pd  = in_sizes[8];            // 256
    const int hd  = in_sizes[7] / pd;       // 1024
    const int seq = 2048;
    const int M   = in_sizes[1] / hd;       // 16384

    char* ws = (char*)d_ws;
    unsigned short* enc_bf = (unsigned short*)ws;            ws += (size_t)M * pd * 2;  // 8 MB
    float*          logit  = (float*)ws;                     ws += (size_t)M * 4;       // 64 KB
    unsigned short* Btw    = (unsigned short*)ws;            ws += (size_t)pd * hd * 2; // 512 KB
    int*            cnt    = (int*)ws;                       ws += 256 * 4;
    int*            off    = (int*)ws;                       ws += 256 * 4;
    int*            perm   = (int*)ws;                       ws += (size_t)2 * Q * 4;   // 64 KB

    hipMemsetAsync(logit, 0, (size_t)M * sizeof(float), stream);
    hipMemsetAsync(cnt, 0, 256 * sizeof(int), stream);

    hist_kernel<<<(2 * Q + 255) / 256, 256, 0, stream>>>(s1, s2, qb, cnt, Q);
    scan_kernel<<<1, 256, 0, stream>>>(cnt, off);
    scatter_kernel<<<(2 * Q + 255) / 256, 256, 0, stream>>>(s1, s2, qb, off, perm, Q);

    transpose_b_kernel<<<(hd / 32) * (pd / 32), 256, 0, stream>>>(proj_w, Btw, hd, pd);
    gemm_mfma_kernel<<<(M / 64) * (pd / 32), 256, 0, stream>>>(
        enc_in, Btw, proj_b, attn_w, enc_bf, logit, M, pd, hd);
    span_kernel<<<2 * Q / 4, 256, 0, stream>>>(
        enc_bf, logit, s1, e1, s2, e2, qb, perm, out, Q, seq, pd);
}

// Round 7
// 177.074 us; speedup vs baseline: 1.1789x; 1.1789x over previous
//
#include <hip/hip_runtime.h>

typedef __attribute__((ext_vector_type(8))) short bf16x8;
typedef __attribute__((ext_vector_type(4))) float f32x4;

__device__ __forceinline__ float bf2f(unsigned short u) {
    union { unsigned int i; float f; } v; v.i = ((unsigned int)u) << 16; return v.f;
}
__device__ __forceinline__ unsigned short f2bf(float f) {
    union { float f; unsigned int i; } v; v.f = f;
    unsigned int x = v.i;
    return (unsigned short)((x + 0x7FFFu + ((x >> 16) & 1u)) >> 16);  // RNE
}
__device__ __forceinline__ void gload16(const void* g, void* l) {
    __builtin_amdgcn_global_load_lds(
        (const __attribute__((address_space(1))) unsigned int*)g,
        (__attribute__((address_space(3))) unsigned int*)l, 16, 0, 0);
}

#define ASM_LGKM0 { asm volatile("s_waitcnt lgkmcnt(0)" ::: "memory"); \
                    __builtin_amdgcn_sched_barrier(0); }
#define ASM_VM(N) asm volatile("s_waitcnt vmcnt(" #N ")" ::: "memory")
#define ASM_BAR   asm volatile("s_barrier" ::: "memory")

// ---------------------------------------------------------------------------
// Bt[n][k] = bf16(B[k][n]);  B = proj_w [K=1024][N=256]
// ---------------------------------------------------------------------------
__global__ __launch_bounds__(256) void transpose_b_kernel(
    const float* __restrict__ B, unsigned short* __restrict__ Bt, int K, int N)
{
    __shared__ float tile[32][33];
    int kb = blockIdx.x % (K / 32);
    int nb = blockIdx.x / (K / 32);
    int k0 = kb * 32, n0 = nb * 32;
    int tx = threadIdx.x & 31, ty = threadIdx.x >> 5;
    #pragma unroll
    for (int i = 0; i < 4; ++i)
        tile[ty + 8 * i][tx] = B[(size_t)(k0 + ty + 8 * i) * N + n0 + tx];
    __syncthreads();
    #pragma unroll
    for (int i = 0; i < 4; ++i)
        Bt[(size_t)(n0 + ty + 8 * i) * K + k0 + tx] = f2bf(tile[tx][ty + 8 * i]);
}

// ---------------------------------------------------------------------------
// enc_bf = bf16(A @ B + bias); logit[row] += row-dot with attn_w (atomic).
// BM=64, BN=128, BK=64, 4 waves (wave w: rows (w&1)*32, cols (w>>1)*64).
// A: global->reg direct (fp32, cvt in reg), 2-slot rotating queue.
// B: global_load_lds, 3 LDS buffers, issued 2 iterations ahead, XOR-swizzled
//    via pre-swizzled source. One raw s_barrier + vmcnt(12) per iteration.
// Grid = (M/64)*(N/128) = 512 blocks.
// ---------------------------------------------------------------------------
__global__ __launch_bounds__(256, 2) void gemm_mfma_kernel(
    const float* __restrict__ A, const unsigned short* __restrict__ Bt,
    const float* __restrict__ bias, const float* __restrict__ attn_w,
    unsigned short* __restrict__ C, float* __restrict__ logit,
    int M, int N, int K)
{
    __shared__ __attribute__((aligned(16))) char BufB[3 * 16384];  // 3 x (128 x 64 bf16)

    const int tid = threadIdx.x;
    const int bid = blockIdx.x;
    // XCD swizzle: 512 = 8 * 64, bijective. XCD x gets 32 bm-panels x 2 bn.
    const int xcd = bid & 7;
    const int j   = bid >> 3;              // 0..63
    const int bn  = (j & 1) * 128;
    const int bm  = (xcd * 32 + (j >> 1)) * 64;

    const int lane = tid & 63;
    const int wave = tid >> 6;
    const int wr = (wave & 1) * 32;
    const int wc = (wave >> 1) * 64;
    const int c15 = lane & 15;
    const int g4  = lane >> 4;

    // A direct-frag pointers: frag (mf, ks) rows wr+mf*16+c15, k = t*64+ks*32+g4*8
    const float* Ar0 = A + (size_t)(bm + wr + c15) * K + g4 * 8;
    const float* Ar1 = A + (size_t)(bm + wr + 16 + c15) * K + g4 * 8;

    // B staging source (pre-swizzled): lane covers n = wave*32 + i*8 + (lane>>3),
    // slot' = lane&7 holds source slot slot'^(n&7)
    const int bn_l   = wave * 32 + (lane >> 3);
    const int bslot  = (lane & 7) ^ ((lane >> 3) & 7);
    const unsigned short* Bsrc = Bt + (size_t)(bn + bn_l) * K + bslot * 8;
    char* ldsW = BufB + wave * 4096;       // + bufoff + i*1024 per round

    // B frag read offsets (bytes): n = wc+nf*16+c15, slot = (ks*4+g4)^(c15&7)
    int offB[4][2];
    #pragma unroll
    for (int nf = 0; nf < 4; ++nf)
        #pragma unroll
        for (int ks = 0; ks < 2; ++ks)
            offB[nf][ks] = (wc + nf * 16 + c15) * 128 + (((ks * 4 + g4) ^ (c15 & 7)) * 16);

    f32x4 acc[2][4];
    #pragma unroll
    for (int mf = 0; mf < 2; ++mf)
        #pragma unroll
        for (int nf = 0; nf < 4; ++nf)
            acc[mf][nf] = (f32x4){0.f, 0.f, 0.f, 0.f};

    float4 aq0[8], aq1[8];   // 2 rotating A slots: [mf*4 + ks*2 + half]
    const int nk = K / 64;   // 16

#define ISSUE_A(T, AQ)                                                        \
    {                                                                         \
        const float* a0 = Ar0 + (T) * 64;                                     \
        const float* a1 = Ar1 + (T) * 64;                                     \
        AQ[0] = *(const float4*)(a0);       AQ[1] = *(const float4*)(a0 + 4); \
        AQ[2] = *(const float4*)(a0 + 32);  AQ[3] = *(const float4*)(a0 + 36);\
        AQ[4] = *(const float4*)(a1);       AQ[5] = *(const float4*)(a1 + 4); \
        AQ[6] = *(const float4*)(a1 + 32);  AQ[7] = *(const float4*)(a1 + 36);\
    }
#define ISSUE_B(T, BOFF)                                                      \
    {                                                                         \
        const unsigned short* s = Bsrc + (T) * 64;                            \
        char* d = ldsW + (BOFF);                                              \
        gload16(s,             d);                                            \
        gload16(s +  8 * K,    d + 1024);                                     \
        gload16(s + 16 * K,    d + 2048);                                     \
        gload16(s + 24 * K,    d + 3072);                                     \
    }
#define CVT_MFMA(AQ, BROFF)                                                   \
    {                                                                         \
        bf16x8 bfr[4][2];                                                     \
        _Pragma("unroll")                                                     \
        for (int nf = 0; nf < 4; ++nf)                                        \
            _Pragma("unroll")                                                 \
            for (int ks = 0; ks < 2; ++ks)                                    \
                bfr[nf][ks] = *(bf16x8*)(BufB + (BROFF) + offB[nf][ks]);      \
        bf16x8 afr[2][2];                                                     \
        _Pragma("unroll")                                                     \
        for (int mf = 0; mf < 2; ++mf)                                        \
            _Pragma("unroll")                                                 \
            for (int ks = 0; ks < 2; ++ks) {                                  \
                unsigned short tmp[8];                                        \
                const float* f0 = (const float*)&AQ[mf * 4 + ks * 2];         \
                _Pragma("unroll")                                             \
                for (int i = 0; i < 8; ++i) tmp[i] = f2bf(f0[i]);             \
                afr[mf][ks] = *(bf16x8*)&tmp[0];                              \
            }                                                                 \
        ASM_LGKM0;                                                            \
        __builtin_amdgcn_s_setprio(1);                                        \
        _Pragma("unroll")                                                     \
        for (int ks = 0; ks < 2; ++ks)                                        \
            _Pragma("unroll")                                                 \
            for (int mf = 0; mf < 2; ++mf)                                    \
                _Pragma("unroll")                                             \
                for (int nf = 0; nf < 4; ++nf)                                \
                    acc[mf][nf] = __builtin_amdgcn_mfma_f32_16x16x32_bf16(    \
                        afr[mf][ks], bfr[nf][ks], acc[mf][nf], 0, 0, 0);      \
        __builtin_amdgcn_s_setprio(0);                                        \
    }

    // ---- prologue: issue batches 0 and 1 (12 vm-ops each) ----
    ISSUE_A(0, aq0) ISSUE_B(0, 0)
    ISSUE_A(1, aq1) ISSUE_B(1, 16384)

    int br = 0, bw = 32768;  // read buf for t, write buf for t+2

#define BODY(T, AQ)                                                           \
    {                                                                         \
        ASM_VM(12);   /* batch T retired; T+1 (12 ops) still in flight */     \
        ASM_BAR;      /* all waves' B(T) parts are in LDS */                  \
        if ((T) + 2 < nk) {                                                   \
            ISSUE_B((T) + 2, bw)                                              \
        }                                                                     \
        CVT_MFMA(AQ, br)                                                      \
        if ((T) + 2 < nk) {                                                   \
            ISSUE_A((T) + 2, AQ)                                              \
        }                                                                     \
        br += 16384; if (br == 49152) br = 0;                                 \
        bw += 16384; if (bw == 49152) bw = 0;                                 \
    }

    int t = 0;
    for (; t + 2 < nk; t += 2) {
        BODY(t, aq0)
        BODY(t + 1, aq1)
    }
    BODY(t, aq0)         // t = nk-2 (no new issues)
    // final iteration: drain everything
    ASM_VM(0);
    ASM_BAR;
    CVT_MFMA(aq1, br)

#undef BODY
#undef ISSUE_A
#undef ISSUE_B
#undef CVT_MFMA

    // ---- epilogue: C store + fused logit partials ----
    const int row0 = bm + wr + g4 * 4;
    const int colb = bn + wc + c15;
    float wsum[2][4] = {};
    #pragma unroll
    for (int nf = 0; nf < 4; ++nf) {
        float bv  = bias[colb + nf * 16];
        float awv = attn_w[colb + nf * 16];
        #pragma unroll
        for (int mf = 0; mf < 2; ++mf) {
            #pragma unroll
            for (int i = 0; i < 4; ++i) {
                float cf = acc[mf][nf][i] + bv;
                C[(size_t)(row0 + mf * 16 + i) * N + colb + nf * 16] = f2bf(cf);
                wsum[mf][i] += cf * awv;
            }
        }
    }
    #pragma unroll
    for (int mf = 0; mf < 2; ++mf) {
        #pragma unroll
        for (int i = 0; i < 4; ++i) {
            float v = wsum[mf][i];
            v += __shfl_xor(v, 1, 64);
            v += __shfl_xor(v, 2, 64);
            v += __shfl_xor(v, 4, 64);
            v += __shfl_xor(v, 8, 64);
            if (c15 == 0) atomicAdd(&logit[row0 + mf * 16 + i], v);
        }
    }
}

// ---------------------------------------------------------------------------
// Span attention: ONE WAVE per query, 16-deep hoisted loads (index-clamped).
// ---------------------------------------------------------------------------
__global__ __launch_bounds__(256) void span_kernel(
    const unsigned short* __restrict__ enc, const float* __restrict__ logit,
    const int* __restrict__ s1, const int* __restrict__ e1,
    const int* __restrict__ s2, const int* __restrict__ e2,
    const int* __restrict__ qb, float* __restrict__ out,
    int Q, int seq, int pd)
{
    int lane = threadIdx.x & 63;
    int q = blockIdx.x * 4 + (threadIdx.x >> 6);
    int r  = (q >= Q) ? 1 : 0;
    int qi = q - r * Q;
    int s = r ? s2[qi] : s1[qi];
    int e = r ? e2[qi] : e1[qi];
    int b = qb[qi];
    int len = e - s + 1;                     // 1..32

    const float* lp = logit + (size_t)b * seq + s;
    float lg = (lane < len) ? lp[lane] : -3.4e38f;
    float m = lg;
    #pragma unroll
    for (int off = 32; off; off >>= 1) m = fmaxf(m, __shfl_xor(m, off, 64));
    float p = (lane < len) ? __expf(lg - m) : 0.0f;
    float sum = p;
    #pragma unroll
    for (int off = 32; off; off >>= 1) sum += __shfl_xor(sum, off, 64);
    float inv = 1.0f / sum;

    const unsigned short* ep = enc + ((size_t)b * seq + s) * pd + lane * 4;
    float ax = 0.f, ay = 0.f, az = 0.f, aw = 0.f;

    for (int t0 = 0; t0 < len; t0 += 16) {       // at most 2 chunks
        ushort4 ev[16];
        #pragma unroll
        for (int u = 0; u < 16; ++u) {
            int tc = t0 + u;
            tc = (tc < len) ? tc : (len - 1);    // clamp: avoid NaN from overread
            ev[u] = *(const ushort4*)(ep + (size_t)tc * pd);
        }
        #pragma unroll
        for (int u = 0; u < 16; ++u) {
            float wt = __shfl(p, t0 + u, 64);    // p==0 beyond len
            ax += wt * bf2f(ev[u].x);
            ay += wt * bf2f(ev[u].y);
            az += wt * bf2f(ev[u].z);
            aw += wt * bf2f(ev[u].w);
        }
    }
    float4 res = {ax * inv, ay * inv, az * inv, aw * inv};
    *((float4*)(out + (size_t)q * pd) + lane) = res;
}

// ---------------------------------------------------------------------------
extern "C" void kernel_launch(void* const* d_in, const int* in_sizes, int n_in,
                              void* d_out, int out_size, void* d_ws, size_t ws_size,
                              hipStream_t stream) {
    const float* enc_in = (const float*)d_in[1];
    const int*   s1     = (const int*)d_in[2];
    const int*   e1     = (const int*)d_in[3];
    const int*   qb     = (const int*)d_in[4];
    const int*   s2     = (const int*)d_in[5];
    const int*   e2     = (const int*)d_in[6];
    const float* proj_w = (const float*)d_in[7];
    const float* proj_b = (const float*)d_in[8];
    const float* attn_w = (const float*)d_in[9];
    float* out = (float*)d_out;

    const int Q   = in_sizes[2];            // 8192
    const int pd  = in_sizes[8];            // 256
    const int hd  = in_sizes[7] / pd;       // 1024
    const int seq = 2048;
    const int M   = in_sizes[1] / hd;       // 16384

    char* ws = (char*)d_ws;
    unsigned short* enc_bf = (unsigned short*)ws;   ws += (size_t)M * pd * 2;   // 8 MB
    float*          logit  = (float*)ws;            ws += (size_t)M * 4;        // 64 KB
    unsigned short* Btw    = (unsigned short*)ws;   ws += (size_t)pd * hd * 2;  // 512 KB

    hipMemsetAsync(logit, 0, (size_t)M * sizeof(float), stream);
    transpose_b_kernel<<<(hd / 32) * (pd / 32), 256, 0, stream>>>(proj_w, Btw, hd, pd);
    gemm_mfma_kernel<<<(M / 64) * (pd / 128), 256, 0, stream>>>(
        enc_in, Btw, proj_b, attn_w, enc_bf, logit, M, pd, hd);
    span_kernel<<<2 * Q / 4, 256, 0, stream>>>(
        enc_bf, logit, s1, e1, s2, e2, qb, out, Q, seq, pd);
}